// Round 15
// baseline (88.348 us; speedup 1.0000x reference)
//
#include <hip/hip_runtime.h>

#define HWD (512*512)
#define Wd 512
#define Hd 512
#define Cd 256
#define Kd 21
#define Nd 2560
#define NSTRIP 4
#define SROWS 128   // rows per strip

// ---------------------------------------------------------------------------
// Wave64 inclusive scan on the VALU pipe via DPP (no ds_bpermute).
// ---------------------------------------------------------------------------
__device__ __forceinline__ float dpp_scan_incl(float x) {
    int xi, t;
    xi = __float_as_int(x);
    t = __builtin_amdgcn_update_dpp(0, xi, 0x111, 0xf, 0xf, true);  // row_shr:1
    x += __int_as_float(t);
    xi = __float_as_int(x);
    t = __builtin_amdgcn_update_dpp(0, xi, 0x112, 0xf, 0xf, true);  // row_shr:2
    x += __int_as_float(t);
    xi = __float_as_int(x);
    t = __builtin_amdgcn_update_dpp(0, xi, 0x114, 0xf, 0xf, true);  // row_shr:4
    x += __int_as_float(t);
    xi = __float_as_int(x);
    t = __builtin_amdgcn_update_dpp(0, xi, 0x118, 0xf, 0xf, true);  // row_shr:8
    x += __int_as_float(t);
    xi = __float_as_int(x);
    t = __builtin_amdgcn_update_dpp(0, xi, 0x142, 0xa, 0xf, false); // bcast:15 -> rows 1,3
    x += __int_as_float(t);
    xi = __float_as_int(x);
    t = __builtin_amdgcn_update_dpp(0, xi, 0x143, 0xc, 0xf, false); // bcast:31 -> rows 2,3
    x += __int_as_float(t);
    return x;
}

// ---------------------------------------------------------------------------
// k_events (single block): event build.  Event = box edge at integral row r:
// at r=y1-1 contribute +(S[r][x1-1]-S[r][x0-1]); at r=y0-1 (if y0>0) the
// negative.  ev = n (12b) | row<<12 (9b) | sign<<31, bucketed per row.
// This is k_ipool's ONLY dependency -> minimal serial prefix (~2us).
// ---------------------------------------------------------------------------
__global__ __launch_bounds__(512) void k_events(const int* __restrict__ boxes,
                                                int* __restrict__ ev_start,
                                                unsigned int* __restrict__ ev_list) {
    const int t = threadIdx.x;
    __shared__ int cnt[512];
    __shared__ int cur[512];
    __shared__ int tt[8];
    const int lane = t & 63, wv = t >> 6;
    cnt[t] = 0;
    __syncthreads();
    for (int n = t; n < Nd; n += 512) {
        const int y0 = boxes[n * 4 + 1];
        const int y1 = boxes[n * 4 + 3];
        if (y0 > 0) atomicAdd(&cnt[y0 - 1], 1);
        atomicAdd(&cnt[y1 - 1], 1);
    }
    __syncthreads();
    const int v = cnt[t];
    int inc = v;
    #pragma unroll
    for (int d = 1; d < 64; d <<= 1) {
        int u = __shfl_up(inc, d);
        if (lane >= d) inc += u;
    }
    if (lane == 63) tt[wv] = inc;
    __syncthreads();
    int off = 0;
    #pragma unroll
    for (int w = 0; w < 8; ++w) if (w < wv) off += tt[w];
    inc += off;
    cur[t] = inc - v;
    ev_start[t] = inc - v;
    if (t == 511) ev_start[512] = inc;
    __syncthreads();
    for (int n = t; n < Nd; n += 512) {
        const int y0 = boxes[n * 4 + 1];
        const int y1 = boxes[n * 4 + 3];
        if (y0 > 0) {
            const int r = y0 - 1;
            const int p = atomicAdd(&cur[r], 1);
            ev_list[p] = (unsigned)n | ((unsigned)r << 12) | 0x80000000u;
        }
        const int r = y1 - 1;
        const int p = atomicAdd(&cur[r], 1);
        ev_list[p] = (unsigned)n | ((unsigned)r << 12);
    }
}

// ---------------------------------------------------------------------------
// k_ipool.  Blocks 0..127: argmax of CAM -> u8 map (4 px/thread, float4) --
// independent streaming work that retires during the ipool occupancy ramp
// instead of serializing in its own launch (map consumed only by k_post).
// Blocks 128..1151: fused strip-local integral + ROI corner consumption
// (3-barrier slab, depth-2 prefetch, DPP scan; 4 blocks/CU, 32 waves/CU).
// Race-free: a box's two events are >= 8 rows apart -> different slabs ->
// barrier-ordered; unique writer per pool_acc slot -> deterministic.
// ---------------------------------------------------------------------------
__global__ __launch_bounds__(512) void k_ipool(const float* __restrict__ f,
                                               const float* __restrict__ ncb,
                                               const int* __restrict__ boxes,
                                               const int* __restrict__ ev_start,
                                               const unsigned int* __restrict__ ev_list,
                                               unsigned char* __restrict__ map,
                                               float* __restrict__ pool_acc) {
    const int t = threadIdx.x;

    if (blockIdx.x < 128) {
        // ---- argmax, vectorized x4 (first-max-wins, strict >) ----
        const int q = blockIdx.x * 512 + t;          // quad index
        float4 best = *(const float4*)(ncb + (size_t)q * 4);
        int b0 = 0, b1 = 0, b2 = 0, b3 = 0;
        #pragma unroll
        for (int k = 1; k < Kd; ++k) {
            float4 v = *(const float4*)(ncb + (size_t)k * HWD + (size_t)q * 4);
            if (v.x > best.x) { best.x = v.x; b0 = k; }
            if (v.y > best.y) { best.y = v.y; b1 = k; }
            if (v.z > best.z) { best.z = v.z; b2 = k; }
            if (v.w > best.w) { best.w = v.w; b3 = k; }
        }
        uchar4 o = { (unsigned char)b0, (unsigned char)b1,
                     (unsigned char)b2, (unsigned char)b3 };
        *(uchar4*)(map + (size_t)q * 4) = o;
        return;
    }

    // ---- ipool ----
    const int bid   = blockIdx.x - 128;
    const int c     = bid >> 2;
    const int strip = bid & 3;
    const int lane = t & 63, wv = t >> 6;
    const float* F = f + (size_t)c * HWD + (size_t)(strip * SROWS) * Wd;

    __shared__ float S[8][512];      // 16 KB slab (row prefixes -> integral)
    __shared__ float partial[Nd];    // 10 KB per-box accumulated sum

    for (int n = t; n < Nd; n += 512) partial[n] = 0.f;

    float colacc = 0.f;              // thread t = column t vertical accumulator

    // depth-2 prefetch: slabs k+1, k+2 in flight while computing slab k
    const float* rp0 = F + (size_t)wv * Wd + lane * 8;
    float4 a0 = *(const float4*)(rp0);
    float4 b0 = *(const float4*)(rp0 + 4);
    const float* rp1 = F + (size_t)(8 + wv) * Wd + lane * 8;
    float4 a1 = *(const float4*)(rp1);
    float4 b1 = *(const float4*)(rp1 + 4);

    #pragma unroll 2
    for (int yb = 0; yb < SROWS; yb += 8) {
        const bool more2 = (yb + 16 < SROWS);
        float4 na, nb;
        if (more2) {
            const float* np = F + (size_t)(yb + 16 + wv) * Wd + lane * 8;
            na = *(const float4*)(np);
            nb = *(const float4*)(np + 4);
        }

        // phase R: row prefix (lane-serial 8 + DPP wave scan of lane totals)
        float v0 = a0.x, v1 = v0 + a0.y, v2 = v1 + a0.z, v3 = v2 + a0.w;
        float v4 = v3 + b0.x, v5 = v4 + b0.y, v6 = v5 + b0.z, v7 = v6 + b0.w;
        const float xx = dpp_scan_incl(v7);
        const float off = xx - v7;   // exclusive prefix of lane totals
        float4 o0 = { v0 + off, v1 + off, v2 + off, v3 + off };
        float4 o1 = { v4 + off, v5 + off, v6 + off, v7 + off };
        *(float4*)&S[wv][lane * 8]     = o0;
        *(float4*)&S[wv][lane * 8 + 4] = o1;
        __syncthreads();                           // sync1: row prefixes ready

        // phase C: vertical integration (batched reads, then prefix+writes)
        float sv[8];
        #pragma unroll
        for (int j = 0; j < 8; ++j) sv[j] = S[j][t];
        #pragma unroll
        for (int j = 0; j < 8; ++j) {
            colacc += sv[j];
            S[j][t] = colacc;
        }
        __syncthreads();                           // sync2: integral ready

        // phase E: consume this slab's box-edge events
        const int g0 = strip * SROWS + yb;
        const int e0 = ev_start[g0];
        const int e1 = ev_start[g0 + 8];
        for (int e = e0 + t; e < e1; e += 512) {
            const unsigned ev = ev_list[e];
            const int n  = ev & 0xFFF;
            const int rr = (ev >> 12) & 7;
            const int x0 = boxes[n * 4 + 0];
            const int x1 = boxes[n * 4 + 2];
            const float sx1 = S[rr][x1 - 1];
            const float sx0 = (x0 > 0) ? S[rr][x0 - 1] : 0.f;
            const float d = sx1 - sx0;
            partial[n] += (ev & 0x80000000u) ? -d : d;
        }
        __syncthreads();                           // sync3: S reusable

        a0 = a1; b0 = b1;
        if (more2) { a1 = na; b1 = nb; }
    }

    // cross-strip fold + coalesced writeout [strip][c][n]
    S[0][t] = colacc;                // strip total column sums
    __syncthreads();
    for (int n = t; n < Nd; n += 512) {
        const int x0 = boxes[n * 4 + 0];
        const int y0 = boxes[n * 4 + 1];
        const int x1 = boxes[n * 4 + 2];
        const int y1 = boxes[n * 4 + 3];
        float p = partial[n];
        const float tdiff = S[0][x1 - 1] - ((x0 > 0) ? S[0][x0 - 1] : 0.f);
        if (strip < ((y1 - 1) >> 7)) p += tdiff;
        if (y0 > 0 && strip < ((y0 - 1) >> 7)) p -= tdiff;
        pool_acc[((size_t)(strip * Cd + c)) * Nd + n] = p;
    }
}

// ---------------------------------------------------------------------------
// k_post.  Blocks 0..79: pool finalize (strip-sum + LDS transpose, both
// sides coalesced).  Blocks 80..2639: fg_score, one BLOCK per box, 8 waves
// split rows; overlaps the pool2 blocks.  Exact integer count == reference.
// ---------------------------------------------------------------------------
__global__ __launch_bounds__(512) void k_post(const float* __restrict__ pool_acc,
                                              const unsigned char* __restrict__ map,
                                              const int* __restrict__ boxes,
                                              const int* __restrict__ labels,
                                              float* __restrict__ pool,
                                              float* __restrict__ fg) {
    const int bid = blockIdx.x;
    const int t = threadIdx.x;
    __shared__ float P[32][257];     // +1 pad: conflict-free transpose
    __shared__ float rarea[32];
    __shared__ int   sred[8];

    if (bid >= Nd / 32) {
        // ---- fg: one block per box, 8 waves over rows ----
        const int n = bid - Nd / 32;
        const int x0 = boxes[n * 4 + 0];
        const int y0 = boxes[n * 4 + 1];
        const int x1 = boxes[n * 4 + 2];
        const int y1 = boxes[n * 4 + 3];
        const int lab = labels[n];
        const int lane = t & 63, wv = t >> 6;
        const int w = x1 - x0;

        int cnt = 0;
        for (int yy = y0 + wv; yy < y1; yy += 8) {
            if (lane < w)
                cnt += (map[yy * Wd + x0 + lane] == lab) ? 1 : 0;
        }
        #pragma unroll
        for (int d = 32; d; d >>= 1) cnt += __shfl_down(cnt, d);
        if (lane == 0) sred[wv] = cnt;
        __syncthreads();
        if (t == 0) {
            int tot = 0;
            #pragma unroll
            for (int i = 0; i < 8; ++i) tot += sred[i];
            fg[n] = (float)tot / (float)(w * (y1 - y0));
        }
        return;
    }

    // ---- pool finalize ----
    const int n0 = bid * 32;
    if (t < 32) {
        const int x0 = boxes[(n0 + t) * 4 + 0];
        const int y0 = boxes[(n0 + t) * 4 + 1];
        const int x1 = boxes[(n0 + t) * 4 + 2];
        const int y1 = boxes[(n0 + t) * 4 + 3];
        rarea[t] = 1.f / (float)((x1 - x0) * (y1 - y0));
    }

    const int ni = t & 31, ci = t >> 5;        // 16 c-lanes x 32 n
    #pragma unroll
    for (int co = 0; co < 16; ++co) {
        const int c = co * 16 + ci;
        float v = 0.f;
        #pragma unroll
        for (int s = 0; s < NSTRIP; ++s)
            v += pool_acc[((size_t)(s * Cd + c)) * Nd + n0 + ni];
        P[ni][c] = v;
    }
    __syncthreads();

    const int c = t & 255, nn = t >> 8;        // 2 n x 256 c
    #pragma unroll
    for (int no = 0; no < 16; ++no) {
        const int i = no * 2 + nn;
        pool[(size_t)(n0 + i) * Cd + c] = P[i][c] * rarea[i];
    }
}

extern "C" void kernel_launch(void* const* d_in, const int* in_sizes, int n_in,
                              void* d_out, int out_size, void* d_ws, size_t ws_size,
                              hipStream_t stream) {
    (void)in_sizes; (void)n_in; (void)out_size; (void)ws_size;

    const float* feature_map = (const float*)d_in[0];   // [256][512][512] f32
    const float* norm_cam_bg = (const float*)d_in[1];   // [21][512][512]  f32
    const int*   boxes       = (const int*)d_in[2];     // [2560][4] i32
    const int*   labels      = (const int*)d_in[3];     // [2560]    i32

    float* out_pool = (float*)d_out;                    // [2560][256]
    float* out_fg   = out_pool + (size_t)Nd * Cd;       // [2560]

    // d_ws layout (all rewritten every call; no state carried across calls)
    char* ws = (char*)d_ws;
    unsigned char* map      = (unsigned char*)ws;                   // 256 KB
    int*           ev_start = (int*)(ws + 262144);                  // 513 int
    unsigned int*  ev_list  = (unsigned int*)(ws + 266240);         // <=5120 u32
    float*         pool_acc = (float*)(ws + 286720);                // 4*256*2560 f32 = 10.5 MB

    k_events<<<1, 512, 0, stream>>>(boxes, ev_start, ev_list);
    k_ipool<<<128 + Cd * NSTRIP, 512, 0, stream>>>(feature_map, norm_cam_bg, boxes,
                                                   ev_start, ev_list, map, pool_acc);
    k_post<<<Nd / 32 + Nd, 512, 0, stream>>>(pool_acc, map, boxes, labels,
                                             out_pool, out_fg);
}

// Round 16
// 76.654 us; speedup vs baseline: 1.1526x; 1.1526x over previous
//
#include <hip/hip_runtime.h>

#define HWD (512*512)
#define Wd 512
#define Hd 512
#define Cd 256
#define Kd 21
#define Nd 2560
#define NSTRIP 4
#define SROWS 128   // rows per strip

// ---------------------------------------------------------------------------
// Wave64 inclusive scan on the VALU pipe via DPP (no ds_bpermute).
// ---------------------------------------------------------------------------
__device__ __forceinline__ float dpp_scan_incl(float x) {
    int xi, t;
    xi = __float_as_int(x);
    t = __builtin_amdgcn_update_dpp(0, xi, 0x111, 0xf, 0xf, true);  // row_shr:1
    x += __int_as_float(t);
    xi = __float_as_int(x);
    t = __builtin_amdgcn_update_dpp(0, xi, 0x112, 0xf, 0xf, true);  // row_shr:2
    x += __int_as_float(t);
    xi = __float_as_int(x);
    t = __builtin_amdgcn_update_dpp(0, xi, 0x114, 0xf, 0xf, true);  // row_shr:4
    x += __int_as_float(t);
    xi = __float_as_int(x);
    t = __builtin_amdgcn_update_dpp(0, xi, 0x118, 0xf, 0xf, true);  // row_shr:8
    x += __int_as_float(t);
    xi = __float_as_int(x);
    t = __builtin_amdgcn_update_dpp(0, xi, 0x142, 0xa, 0xf, false); // bcast:15 -> rows 1,3
    x += __int_as_float(t);
    xi = __float_as_int(x);
    t = __builtin_amdgcn_update_dpp(0, xi, 0x143, 0xc, 0xf, false); // bcast:31 -> rows 2,3
    x += __int_as_float(t);
    return x;
}

// ---------------------------------------------------------------------------
// k_pre.  Blocks 0..127: argmax of CAM -> u8 map, 4 px/thread via float4
// (first-max-wins, strict >, k ascending).  Block 128: event build.
// ev = n (12b) | row<<12 (9b) | sign<<31, bucketed per row.
// ---------------------------------------------------------------------------
__global__ __launch_bounds__(512) void k_pre(const float* __restrict__ ncb,
                                             const int* __restrict__ boxes,
                                             unsigned char* __restrict__ map,
                                             int* __restrict__ ev_start,
                                             unsigned int* __restrict__ ev_list) {
    const int t = threadIdx.x;
    if (blockIdx.x < 128) {
        // ---- argmax, vectorized x4 ----
        const int q = blockIdx.x * 512 + t;          // quad index
        float4 best = *(const float4*)(ncb + (size_t)q * 4);
        int b0 = 0, b1 = 0, b2 = 0, b3 = 0;
        #pragma unroll
        for (int k = 1; k < Kd; ++k) {
            float4 v = *(const float4*)(ncb + (size_t)k * HWD + (size_t)q * 4);
            if (v.x > best.x) { best.x = v.x; b0 = k; }
            if (v.y > best.y) { best.y = v.y; b1 = k; }
            if (v.z > best.z) { best.z = v.z; b2 = k; }
            if (v.w > best.w) { best.w = v.w; b3 = k; }
        }
        uchar4 o = { (unsigned char)b0, (unsigned char)b1,
                     (unsigned char)b2, (unsigned char)b3 };
        *(uchar4*)(map + (size_t)q * 4) = o;
        return;
    }

    // ---- events (single block) ----
    __shared__ int cnt[512];
    __shared__ int cur[512];
    __shared__ int tt[8];
    const int lane = t & 63, wv = t >> 6;
    cnt[t] = 0;
    __syncthreads();
    for (int n = t; n < Nd; n += 512) {
        const int y0 = boxes[n * 4 + 1];
        const int y1 = boxes[n * 4 + 3];
        if (y0 > 0) atomicAdd(&cnt[y0 - 1], 1);
        atomicAdd(&cnt[y1 - 1], 1);
    }
    __syncthreads();
    const int v = cnt[t];
    int inc = v;
    #pragma unroll
    for (int d = 1; d < 64; d <<= 1) {
        int u = __shfl_up(inc, d);
        if (lane >= d) inc += u;
    }
    if (lane == 63) tt[wv] = inc;
    __syncthreads();
    int off = 0;
    #pragma unroll
    for (int w = 0; w < 8; ++w) if (w < wv) off += tt[w];
    inc += off;
    cur[t] = inc - v;
    ev_start[t] = inc - v;
    if (t == 511) ev_start[512] = inc;
    __syncthreads();
    for (int n = t; n < Nd; n += 512) {
        const int y0 = boxes[n * 4 + 1];
        const int y1 = boxes[n * 4 + 3];
        if (y0 > 0) {
            const int r = y0 - 1;
            const int p = atomicAdd(&cur[r], 1);
            ev_list[p] = (unsigned)n | ((unsigned)r << 12) | 0x80000000u;
        }
        const int r = y1 - 1;
        const int p = atomicAdd(&cur[r], 1);
        ev_list[p] = (unsigned)n | ((unsigned)r << 12);
    }
}

// ---------------------------------------------------------------------------
// Fused strip-local integral + ROI corner consumption (R10 exact: 3-barrier
// slab, depth-2 prefetch, DPP scan, plain cached float4 loads).
// Grid = 256 ch x 4 strips (4 blocks/CU, 32 waves/CU, all co-resident).
// ---------------------------------------------------------------------------
__global__ __launch_bounds__(512) void k_ipool(const float* __restrict__ f,
                                               const int* __restrict__ boxes,
                                               const int* __restrict__ ev_start,
                                               const unsigned int* __restrict__ ev_list,
                                               float* __restrict__ pool_acc) {
    const int c     = blockIdx.x >> 2;
    const int strip = blockIdx.x & 3;
    const int t = threadIdx.x;
    const int lane = t & 63, wv = t >> 6;
    const float* F = f + (size_t)c * HWD + (size_t)(strip * SROWS) * Wd;

    __shared__ float S[8][512];      // 16 KB slab (row prefixes -> integral)
    __shared__ float partial[Nd];    // 10 KB per-box accumulated sum

    for (int n = t; n < Nd; n += 512) partial[n] = 0.f;

    float colacc = 0.f;              // thread t = column t vertical accumulator

    // depth-2 prefetch: slabs k+1, k+2 in flight while computing slab k
    const float* rp0 = F + (size_t)wv * Wd + lane * 8;
    float4 a0 = *(const float4*)(rp0);
    float4 b0 = *(const float4*)(rp0 + 4);
    const float* rp1 = F + (size_t)(8 + wv) * Wd + lane * 8;
    float4 a1 = *(const float4*)(rp1);
    float4 b1 = *(const float4*)(rp1 + 4);

    for (int yb = 0; yb < SROWS; yb += 8) {
        const bool more2 = (yb + 16 < SROWS);
        float4 na, nb;
        if (more2) {
            const float* np = F + (size_t)(yb + 16 + wv) * Wd + lane * 8;
            na = *(const float4*)(np);
            nb = *(const float4*)(np + 4);
        }

        // phase R: row prefix (lane-serial 8 + DPP wave scan of lane totals)
        float v0 = a0.x, v1 = v0 + a0.y, v2 = v1 + a0.z, v3 = v2 + a0.w;
        float v4 = v3 + b0.x, v5 = v4 + b0.y, v6 = v5 + b0.z, v7 = v6 + b0.w;
        const float xx = dpp_scan_incl(v7);
        const float off = xx - v7;   // exclusive prefix of lane totals
        float4 o0 = { v0 + off, v1 + off, v2 + off, v3 + off };
        float4 o1 = { v4 + off, v5 + off, v6 + off, v7 + off };
        *(float4*)&S[wv][lane * 8]     = o0;
        *(float4*)&S[wv][lane * 8 + 4] = o1;
        __syncthreads();                           // sync1: row prefixes ready

        // phase C: vertical integration (batched reads, then prefix+writes)
        float sv[8];
        #pragma unroll
        for (int j = 0; j < 8; ++j) sv[j] = S[j][t];
        #pragma unroll
        for (int j = 0; j < 8; ++j) {
            colacc += sv[j];
            S[j][t] = colacc;
        }
        __syncthreads();                           // sync2: integral ready

        // phase E: consume this slab's box-edge events
        const int g0 = strip * SROWS + yb;
        const int e0 = ev_start[g0];
        const int e1 = ev_start[g0 + 8];
        for (int e = e0 + t; e < e1; e += 512) {
            const unsigned ev = ev_list[e];
            const int n  = ev & 0xFFF;
            const int rr = (ev >> 12) & 7;
            const int x0 = boxes[n * 4 + 0];
            const int x1 = boxes[n * 4 + 2];
            const float sx1 = S[rr][x1 - 1];
            const float sx0 = (x0 > 0) ? S[rr][x0 - 1] : 0.f;
            const float d = sx1 - sx0;
            partial[n] += (ev & 0x80000000u) ? -d : d;
        }
        __syncthreads();                           // sync3: S reusable

        a0 = a1; b0 = b1;
        if (more2) { a1 = na; b1 = nb; }
    }

    // cross-strip fold + coalesced writeout [strip][c][n]
    S[0][t] = colacc;                // strip total column sums
    __syncthreads();
    for (int n = t; n < Nd; n += 512) {
        const int x0 = boxes[n * 4 + 0];
        const int y0 = boxes[n * 4 + 1];
        const int x1 = boxes[n * 4 + 2];
        const int y1 = boxes[n * 4 + 3];
        float p = partial[n];
        const float tdiff = S[0][x1 - 1] - ((x0 > 0) ? S[0][x0 - 1] : 0.f);
        if (strip < ((y1 - 1) >> 7)) p += tdiff;
        if (y0 > 0 && strip < ((y0 - 1) >> 7)) p -= tdiff;
        pool_acc[((size_t)(strip * Cd + c)) * Nd + n] = p;
    }
}

// ---------------------------------------------------------------------------
// k_post.  Blocks 0..79: pool finalize (strip-sum + LDS transpose, both
// sides coalesced).  Blocks 80..2639: fg_score, one BLOCK per box, 8 waves
// split rows; overlaps the pool2 blocks.  Exact integer count == reference.
// ---------------------------------------------------------------------------
__global__ __launch_bounds__(512) void k_post(const float* __restrict__ pool_acc,
                                              const unsigned char* __restrict__ map,
                                              const int* __restrict__ boxes,
                                              const int* __restrict__ labels,
                                              float* __restrict__ pool,
                                              float* __restrict__ fg) {
    const int bid = blockIdx.x;
    const int t = threadIdx.x;
    __shared__ float P[32][257];     // +1 pad: conflict-free transpose
    __shared__ float rarea[32];
    __shared__ int   sred[8];

    if (bid >= Nd / 32) {
        // ---- fg: one block per box, 8 waves over rows ----
        const int n = bid - Nd / 32;
        const int x0 = boxes[n * 4 + 0];
        const int y0 = boxes[n * 4 + 1];
        const int x1 = boxes[n * 4 + 2];
        const int y1 = boxes[n * 4 + 3];
        const int lab = labels[n];
        const int lane = t & 63, wv = t >> 6;
        const int w = x1 - x0;

        int cnt = 0;
        for (int yy = y0 + wv; yy < y1; yy += 8) {
            if (lane < w)
                cnt += (map[yy * Wd + x0 + lane] == lab) ? 1 : 0;
        }
        #pragma unroll
        for (int d = 32; d; d >>= 1) cnt += __shfl_down(cnt, d);
        if (lane == 0) sred[wv] = cnt;
        __syncthreads();
        if (t == 0) {
            int tot = 0;
            #pragma unroll
            for (int i = 0; i < 8; ++i) tot += sred[i];
            fg[n] = (float)tot / (float)(w * (y1 - y0));
        }
        return;
    }

    // ---- pool finalize ----
    const int n0 = bid * 32;
    if (t < 32) {
        const int x0 = boxes[(n0 + t) * 4 + 0];
        const int y0 = boxes[(n0 + t) * 4 + 1];
        const int x1 = boxes[(n0 + t) * 4 + 2];
        const int y1 = boxes[(n0 + t) * 4 + 3];
        rarea[t] = 1.f / (float)((x1 - x0) * (y1 - y0));
    }

    const int ni = t & 31, ci = t >> 5;        // 16 c-lanes x 32 n
    #pragma unroll
    for (int co = 0; co < 16; ++co) {
        const int c = co * 16 + ci;
        float v = 0.f;
        #pragma unroll
        for (int s = 0; s < NSTRIP; ++s)
            v += pool_acc[((size_t)(s * Cd + c)) * Nd + n0 + ni];
        P[ni][c] = v;
    }
    __syncthreads();

    const int c = t & 255, nn = t >> 8;        // 2 n x 256 c
    #pragma unroll
    for (int no = 0; no < 16; ++no) {
        const int i = no * 2 + nn;
        pool[(size_t)(n0 + i) * Cd + c] = P[i][c] * rarea[i];
    }
}

extern "C" void kernel_launch(void* const* d_in, const int* in_sizes, int n_in,
                              void* d_out, int out_size, void* d_ws, size_t ws_size,
                              hipStream_t stream) {
    (void)in_sizes; (void)n_in; (void)out_size; (void)ws_size;

    const float* feature_map = (const float*)d_in[0];   // [256][512][512] f32
    const float* norm_cam_bg = (const float*)d_in[1];   // [21][512][512]  f32
    const int*   boxes       = (const int*)d_in[2];     // [2560][4] i32
    const int*   labels      = (const int*)d_in[3];     // [2560]    i32

    float* out_pool = (float*)d_out;                    // [2560][256]
    float* out_fg   = out_pool + (size_t)Nd * Cd;       // [2560]

    // d_ws layout (all rewritten every call; no state carried across calls)
    char* ws = (char*)d_ws;
    unsigned char* map      = (unsigned char*)ws;                   // 256 KB
    int*           ev_start = (int*)(ws + 262144);                  // 513 int
    unsigned int*  ev_list  = (unsigned int*)(ws + 266240);         // <=5120 u32
    float*         pool_acc = (float*)(ws + 286720);                // 4*256*2560 f32 = 10.5 MB

    k_pre<<<129, 512, 0, stream>>>(norm_cam_bg, boxes, map, ev_start, ev_list);
    k_ipool<<<Cd * NSTRIP, 512, 0, stream>>>(feature_map, boxes, ev_start, ev_list,
                                             pool_acc);
    k_post<<<Nd / 32 + Nd, 512, 0, stream>>>(pool_acc, map, boxes, labels,
                                             out_pool, out_fg);
}